// Round 1
// baseline (115.769 us; speedup 1.0000x reference)
//
#include <hip/hip_runtime.h>
#include <math.h>

#define DIM 64
#define HEADS 4
#define BB 8
#define QQ 128
#define VV 128
#define NN (BB*QQ)   // 1024

typedef float f2 __attribute__((ext_vector_type(2)));

// ---- DPP helpers (VALU, no DS); CTRL is a compile-time template constant ----
template <int CTRL>
__device__ __forceinline__ float dppf(float x) {
    return __int_as_float(__builtin_amdgcn_update_dpp(
        0, __float_as_int(x), CTRL, 0xF, 0xF, true));
}
#define SWAP1 0xB1   // quad_perm(1,0,3,2): xor-1 partner
#define WSHR1 0x138  // wave_shr:1 : lane j <- j-1
#define WSHL1 0x130  // wave_shl:1 : lane j <- j+1

// ---- compiler-proof prefetch: asm global loads + counted vmcnt + pin ----
// (rule #18: consumer must be fenced by sched_barrier(0) after the waitcnt;
//  the "+v" pin creates an IR-level def so uses cannot float above the wait)
template<int OFF>
__device__ __forceinline__ void gload(f2& d, const f2* p) {
    asm volatile("global_load_dwordx2 %0, %1, off offset:%2"
                 : "=v"(d) : "v"(p), "n"(OFF));
}
__device__ __forceinline__ void issue8(f2* buf, const f2* p) {
    gload<0>(buf[0], p);    gload<512>(buf[1], p);
    gload<1024>(buf[2], p); gload<1536>(buf[3], p);
    gload<2048>(buf[4], p); gload<2560>(buf[5], p);
    gload<3072>(buf[6], p); gload<3584>(buf[7], p);
}
__device__ __forceinline__ void pin8(f2* buf) {
    #pragma unroll
    for (int k = 0; k < 8; ++k) asm volatile("" : "+v"(buf[k]));
    __builtin_amdgcn_sched_barrier(0);
}

// K1: Av[h][row][j] = f32 (re,im) of sum_i values[row,i] * U[h, 64+i, j]
__global__ __launch_bounds__(256) void k_av(const float* __restrict__ values,
                                            const float* __restrict__ U_re,
                                            const float* __restrict__ U_im,
                                            f2* __restrict__ Av) {
    int tid = blockIdx.x * blockDim.x + threadIdx.x;
    int w = tid >> 6;            // 0..2047
    int j = tid & 63;
    int h = w >> 9;              // 0..3
    int r0 = (w & 511) << 1;     // first of 2 rows within head h
    const float* vrow = values + r0 * DIM;                     // wave-uniform
    const float* ur = U_re + (h * 2 * DIM + DIM) * DIM + j;    // bottom half
    const float* ui = U_im + (h * 2 * DIM + DIM) * DIM + j;
    f2 a0 = 0.f, a1 = 0.f;
    #pragma unroll 8
    for (int i = 0; i < DIM; ++i) {
        f2 u; u.x = ur[i * DIM]; u.y = ui[i * DIM];
        a0 += vrow[i] * u;                 // s_load scalars broadcast
        a1 += vrow[DIM + i] * u;
    }
    f2* out = Av + (h * 1024 + r0) * DIM + j;
    out[0] = a0; out[DIM] = a1;
}

// K2: 1024 blocks (one row each) x 4 waves (one head each). Step math is
// unchanged from the verified kernel; the Av feed is now an asm-pinned
// depth-2 register prefetch (16 dwordx2 in flight, vmcnt(8) gate per
// 8-step window) so the scan never exposes L2/L3 latency per step.
__global__ __launch_bounds__(256, 4) void k_rnn_dense(
        const float* __restrict__ queries,
        const float* __restrict__ U_re,
        const float* __restrict__ U_im,
        const float* __restrict__ bias,
        const float* __restrict__ theta1,
        const float* __restrict__ phi1,
        const float* __restrict__ theta2,
        const float* __restrict__ phi2,
        const float* __restrict__ omega,
        const f2* __restrict__ Av,
        const float* __restrict__ W_dense,
        const float* __restrict__ b_dense,
        float* __restrict__ y) {
    int n = blockIdx.x;        // 0..1023 (row)
    int t = threadIdx.x;
    int h = t >> 6;            // head = wave
    int j = t & 63;            // state dim = lane
    int b = n >> 7;

    // ---- layer 1: t = E1 .* (C1*h + S1*swap1(h)) ----
    int k1 = j >> 1;
    float th1 = theta1[h * 32 + k1], ph1 = phi1[h * 32 + k1];
    float C1 = cosf(th1), s1v = sinf(th1);
    float S1, E1r, E1i;
    if ((j & 1) == 0) { S1 = -s1v; E1r = cosf(ph1); E1i = sinf(ph1); }
    else              { S1 =  s1v; E1r = 1.f;       E1i = 0.f;       }

    // ---- layer 2: s = PH .* (C2*t + SL*shl1(t) + SR*shr1(t)) ----
    float C2, SL, SR, p2r, p2i;
    if (j == 0 || j == 63) {
        C2 = 1.f; SL = 0.f; SR = 0.f; p2r = 1.f; p2i = 0.f;
    } else {
        int k2 = (j - 1) >> 1;
        float th2 = theta2[h * 31 + k2], ph2 = phi2[h * 31 + k2];
        float c2 = cosf(th2), s2 = sinf(th2);
        if (j & 1) { C2 = c2; SL = -s2; SR = 0.f; p2r = cosf(ph2); p2i = sinf(ph2); }
        else       { C2 = c2; SR =  s2; SL = 0.f; p2r = 1.f;       p2i = 0.f;       }
    }
    float om = omega[h * 64 + j];
    float eor = cosf(om), eoi = sinf(om);
    float PHr = p2r * eor - p2i * eoi;
    float PHi = p2r * eoi + p2i * eor;
    float bj = bias[h * 64 + j];

    // ---- Aq: uq = q_row . U_top[h]; query row block-uniform -> s_load ----
    const float* qrow = queries + n * DIM;
    const float* ur = U_re + (h * 2 * DIM) * DIM + j;
    const float* ui = U_im + (h * 2 * DIM) * DIM + j;
    float uqr = 0.f, uqi = 0.f;
    #pragma unroll 8
    for (int i = 0; i < DIM; ++i) {
        float a = qrow[i];
        uqr = fmaf(a, ur[i * DIM], uqr);
        uqi = fmaf(a, ui[i * DIM], uqi);
    }

    float hr = 0.f, hi = 0.f;
    auto step = [&](f2 av) {
        float uvr = uqr + av.x;            // off-chain input term
        float uvi = uqi + av.y;
        // layer 1: real Givens + phase (even lanes)
        float pr = dppf<SWAP1>(hr), pi = dppf<SWAP1>(hi);
        float tpr = fmaf(C1, hr, S1 * pr);
        float tpi = fmaf(C1, hi, S1 * pi);
        float Tr = fmaf(E1r, tpr, -E1i * tpi);
        float Ti = fmaf(E1r, tpi,  E1i * tpr);
        // layer 2: real 3-tap + fused phase
        float Lr = dppf<WSHL1>(Tr), Li = dppf<WSHL1>(Ti);
        float Rr = dppf<WSHR1>(Tr), Ri = dppf<WSHR1>(Ti);
        float spr = fmaf(C2, Tr, fmaf(SL, Lr, SR * Rr));
        float spi = fmaf(C2, Ti, fmaf(SL, Li, SR * Ri));
        float zr = fmaf(PHr, spr, fmaf(-PHi, spi, uvr));
        float zi = fmaf(PHr, spi, fmaf( PHi, spr, uvi));
        // modrelu: sc = max(1 + b*rsq(|z|^2+eps), 0)  (1/m == rsq)
        float q2 = fmaf(zr, zr, fmaf(zi, zi, 1e-10f));
        float rs = __builtin_amdgcn_rsqf(q2);
        float sc = fmaxf(fmaf(bj, rs, 1.f), 0.f);
        hr = zr * sc; hi = zi * sc;
    };

    // ---- asm-pinned depth-2 prefetch over 16 windows of 8 steps ----
    const f2* base = Av + (h * 1024 + b * 128) * DIM + j;  // step stride = 512 B
    f2 A[8], Bf[8];
    __builtin_amdgcn_sched_barrier(0);   // keep preamble waits above our issues
    issue8(A,  base);                    // w0
    issue8(Bf, base + 8 * DIM);          // w1
    const f2* pA = base;
    const f2* pB = base + 8 * DIM;

    for (int it = 0; it < 7; ++it) {
        asm volatile("s_waitcnt vmcnt(8)");   // w_{2it} (A) landed
        pin8(A);
        #pragma unroll
        for (int k = 0; k < 8; ++k) step(A[k]);
        pA += 16 * DIM;
        issue8(A, pA);                        // w_{2it+2}
        asm volatile("s_waitcnt vmcnt(8)");   // w_{2it+1} (B) landed
        pin8(Bf);
        #pragma unroll
        for (int k = 0; k < 8; ++k) step(Bf[k]);
        pB += 16 * DIM;
        issue8(Bf, pB);                       // w_{2it+3}
    }
    asm volatile("s_waitcnt vmcnt(8)");       // w14
    pin8(A);
    #pragma unroll
    for (int k = 0; k < 8; ++k) step(A[k]);
    asm volatile("s_waitcnt vmcnt(0)");       // w15 (drain: loop is done)
    pin8(Bf);
    #pragma unroll
    for (int k = 0; k < 8; ++k) step(Bf[k]);

    // ---- fused dense for row n ----
    __shared__ float s_acc[HEADS * DIM];   // 256
    __shared__ float s_part[256];
    s_acc[h * 64 + j] = hr;                // Re(hT)
    __syncthreads();

    {   // thread t: k-quarter qq = t>>6, col jj = t&63
        int qq = t >> 6, jj = t & 63;
        const float* Wp = W_dense + (qq * 64) * DIM + jj;
        const float* ap = &s_acc[qq * 64];
        float part = 0.f;
        #pragma unroll 8
        for (int k = 0; k < 64; ++k)
            part = fmaf(ap[k], Wp[k * DIM], part);   // ap broadcast, Wp coalesced
        s_part[t] = part;
    }
    __syncthreads();
    if (t < 64) {
        y[n * DIM + t] = b_dense[t] + s_part[t] + s_part[64 + t]
                       + s_part[128 + t] + s_part[192 + t];
    }
}

extern "C" void kernel_launch(void* const* d_in, const int* in_sizes, int n_in,
                              void* d_out, int out_size, void* d_ws, size_t ws_size,
                              hipStream_t stream) {
    const float* queries = (const float*)d_in[0];
    const float* values  = (const float*)d_in[1];
    const float* U_re    = (const float*)d_in[2];
    const float* U_im    = (const float*)d_in[3];
    const float* bias    = (const float*)d_in[4];
    const float* theta1  = (const float*)d_in[5];
    const float* phi1    = (const float*)d_in[6];
    const float* theta2  = (const float*)d_in[7];
    const float* phi2    = (const float*)d_in[8];
    const float* omega   = (const float*)d_in[9];
    const float* W_dense = (const float*)d_in[10];
    const float* b_dense = (const float*)d_in[11];
    float* y = (float*)d_out;

    f2* Av = (f2*)d_ws;   // HEADS*1024*64 f2 = 2 MB

    k_av<<<512, 256, 0, stream>>>(values, U_re, U_im, Av);
    k_rnn_dense<<<1024, 256, 0, stream>>>(queries, U_re, U_im, bias, theta1,
                                          phi1, theta2, phi2, omega, Av,
                                          W_dense, b_dense, y);
}

// Round 2
// 112.681 us; speedup vs baseline: 1.0274x; 1.0274x over previous
//
#include <hip/hip_runtime.h>
#include <math.h>

#define DIM 64
#define HEADS 4
#define BB 8
#define QQ 128
#define VV 128
#define NN (BB*QQ)   // 1024

typedef float f2 __attribute__((ext_vector_type(2)));
typedef float f4 __attribute__((ext_vector_type(4)));

// ---- DPP helpers (VALU, no DS); CTRL is a compile-time template constant ----
template <int CTRL>
__device__ __forceinline__ float dppf(float x) {
    return __int_as_float(__builtin_amdgcn_update_dpp(
        0, __float_as_int(x), CTRL, 0xF, 0xF, true));
}
#define SWAP1 0xB1   // quad_perm(1,0,3,2): xor-1 partner
#define WSHR1 0x138  // wave_shr:1 : lane j <- j-1
#define WSHL1 0x130  // wave_shl:1 : lane j <- j+1

// K1: AvP[h][rp][j] = float4 {re,im of row 2rp ; re,im of row 2rp+1}
//     where (re,im)[row][j] = sum_i values[row,i] * U[h, 64+i, j]
// Packing two V-rows per float4 lets K2 fetch two timesteps per dwordx4.
__global__ __launch_bounds__(256) void k_av(const float* __restrict__ values,
                                            const float* __restrict__ U_re,
                                            const float* __restrict__ U_im,
                                            f4* __restrict__ AvP) {
    int tid = blockIdx.x * blockDim.x + threadIdx.x;
    int w = tid >> 6;            // 0..2047
    int j = tid & 63;
    int h = w >> 9;              // 0..3
    int rp = w & 511;            // row pair within head
    int r0 = rp << 1;
    const float* vrow = values + r0 * DIM;                     // wave-uniform
    const float* ur = U_re + (h * 2 * DIM + DIM) * DIM + j;    // bottom half
    const float* ui = U_im + (h * 2 * DIM + DIM) * DIM + j;
    f2 a0 = 0.f, a1 = 0.f;
    #pragma unroll 8
    for (int i = 0; i < DIM; ++i) {
        f2 u; u.x = ur[i * DIM]; u.y = ui[i * DIM];
        a0 += vrow[i] * u;                 // s_load scalars broadcast
        a1 += vrow[DIM + i] * u;
    }
    f4 o; o.x = a0.x; o.y = a0.y; o.z = a1.x; o.w = a1.y;
    AvP[(h * 512 + rp) * 64 + j] = o;      // one dwordx4 store
}

// K2: 512 blocks (block = query-row PAIR 2m,2m+1) x 4 waves (head per wave).
// Both rows of a pair share the same batch b, hence the SAME Av sequence:
// each wave runs TWO independent recurrence chains sharing every Av load.
// 2 blocks/CU -> 2 waves/SIMD x 2 chains = 4 independent chains per SIMD,
// with 2x fewer load/loop instructions per chain than the R=1 version.
__global__ __launch_bounds__(256, 2) void k_rnn_dense(
        const float* __restrict__ queries,
        const float* __restrict__ U_re,
        const float* __restrict__ U_im,
        const float* __restrict__ bias,
        const float* __restrict__ theta1,
        const float* __restrict__ phi1,
        const float* __restrict__ theta2,
        const float* __restrict__ phi2,
        const float* __restrict__ omega,
        const f4* __restrict__ AvP,
        const float* __restrict__ W_dense,
        const float* __restrict__ b_dense,
        float* __restrict__ y) {
    int m = blockIdx.x;        // 0..511 (row pair)
    int n0 = m << 1;           // rows n0, n0+1 (same batch b)
    int t = threadIdx.x;
    int h = t >> 6;            // head = wave
    int j = t & 63;            // state dim = lane
    int b = n0 >> 7;

    // ---- layer 1: t = E1 .* (C1*h + S1*swap1(h)) ----
    int k1 = j >> 1;
    float th1 = theta1[h * 32 + k1], ph1 = phi1[h * 32 + k1];
    float C1 = cosf(th1), s1v = sinf(th1);
    float S1, E1r, E1i;
    if ((j & 1) == 0) { S1 = -s1v; E1r = cosf(ph1); E1i = sinf(ph1); }
    else              { S1 =  s1v; E1r = 1.f;       E1i = 0.f;       }

    // ---- layer 2: s = PH .* (C2*t + SL*shl1(t) + SR*shr1(t)) ----
    float C2, SL, SR, p2r, p2i;
    if (j == 0 || j == 63) {
        C2 = 1.f; SL = 0.f; SR = 0.f; p2r = 1.f; p2i = 0.f;
    } else {
        int k2 = (j - 1) >> 1;
        float th2 = theta2[h * 31 + k2], ph2 = phi2[h * 31 + k2];
        float c2 = cosf(th2), s2 = sinf(th2);
        if (j & 1) { C2 = c2; SL = -s2; SR = 0.f; p2r = cosf(ph2); p2i = sinf(ph2); }
        else       { C2 = c2; SR =  s2; SL = 0.f; p2r = 1.f;       p2i = 0.f;       }
    }
    float om = omega[h * 64 + j];
    float eor = cosf(om), eoi = sinf(om);
    float PHr = p2r * eor - p2i * eoi;
    float PHi = p2r * eoi + p2i * eor;
    float bj = bias[h * 64 + j];

    // ---- Aq for BOTH rows: U column loads shared ----
    const float* q0 = queries + n0 * DIM;        // block-uniform -> s_load
    const float* q1 = q0 + DIM;
    const float* ur = U_re + (h * 2 * DIM) * DIM + j;
    const float* ui = U_im + (h * 2 * DIM) * DIM + j;
    float uq0r = 0.f, uq0i = 0.f, uq1r = 0.f, uq1i = 0.f;
    #pragma unroll 8
    for (int i = 0; i < DIM; ++i) {
        float u_r = ur[i * DIM], u_i = ui[i * DIM];
        float a0 = q0[i], a1 = q1[i];
        uq0r = fmaf(a0, u_r, uq0r);  uq0i = fmaf(a0, u_i, uq0i);
        uq1r = fmaf(a1, u_r, uq1r);  uq1i = fmaf(a1, u_i, uq1i);
    }

    float h0r = 0.f, h0i = 0.f, h1r = 0.f, h1i = 0.f;
    // one timestep for BOTH chains; interleaved for ILP (fills DPP-hazard
    // slots and chain-latency bubbles of the other row)
    auto step = [&](float avr, float avi) {
        float uv0r = uq0r + avr, uv0i = uq0i + avi;
        float uv1r = uq1r + avr, uv1i = uq1i + avi;
        // layer 1
        float p0r = dppf<SWAP1>(h0r), p0i = dppf<SWAP1>(h0i);
        float p1r = dppf<SWAP1>(h1r), p1i = dppf<SWAP1>(h1i);
        float tp0r = fmaf(C1, h0r, S1 * p0r), tp0i = fmaf(C1, h0i, S1 * p0i);
        float tp1r = fmaf(C1, h1r, S1 * p1r), tp1i = fmaf(C1, h1i, S1 * p1i);
        float T0r = fmaf(E1r, tp0r, -E1i * tp0i), T0i = fmaf(E1r, tp0i, E1i * tp0r);
        float T1r = fmaf(E1r, tp1r, -E1i * tp1i), T1i = fmaf(E1r, tp1i, E1i * tp1r);
        // layer 2
        float L0r = dppf<WSHL1>(T0r), L0i = dppf<WSHL1>(T0i);
        float L1r = dppf<WSHL1>(T1r), L1i = dppf<WSHL1>(T1i);
        float R0r = dppf<WSHR1>(T0r), R0i = dppf<WSHR1>(T0i);
        float R1r = dppf<WSHR1>(T1r), R1i = dppf<WSHR1>(T1i);
        float sp0r = fmaf(C2, T0r, fmaf(SL, L0r, SR * R0r));
        float sp0i = fmaf(C2, T0i, fmaf(SL, L0i, SR * R0i));
        float sp1r = fmaf(C2, T1r, fmaf(SL, L1r, SR * R1r));
        float sp1i = fmaf(C2, T1i, fmaf(SL, L1i, SR * R1i));
        float z0r = fmaf(PHr, sp0r, fmaf(-PHi, sp0i, uv0r));
        float z0i = fmaf(PHr, sp0i, fmaf( PHi, sp0r, uv0i));
        float z1r = fmaf(PHr, sp1r, fmaf(-PHi, sp1i, uv1r));
        float z1i = fmaf(PHr, sp1i, fmaf( PHi, sp1r, uv1i));
        // modrelu
        float q20 = fmaf(z0r, z0r, fmaf(z0i, z0i, 1e-10f));
        float q21 = fmaf(z1r, z1r, fmaf(z1i, z1i, 1e-10f));
        float rs0 = __builtin_amdgcn_rsqf(q20);
        float rs1 = __builtin_amdgcn_rsqf(q21);
        float sc0 = fmaxf(fmaf(bj, rs0, 1.f), 0.f);
        float sc1 = fmaxf(fmaf(bj, rs1, 1.f), 0.f);
        h0r = z0r * sc0; h0i = z0i * sc0;
        h1r = z1r * sc1; h1i = z1i * sc1;
    };

    // ---- scan: 64 timestep-pairs, batch-4 (8 steps) register dbuf ----
    const f4* p = AvP + (h * 512 + b * 64) * 64 + j;   // pair stride = 64 f4
    f4 buf[4], nxt[4];
    #pragma unroll
    for (int k = 0; k < 4; ++k) buf[k] = p[k * 64];

    for (int w = 0; w < 16; ++w) {
        const f4* pn = p + ((w < 15) ? 4 * 64 : 0);
        #pragma unroll
        for (int k = 0; k < 4; ++k) nxt[k] = pn[k * 64];
        p = pn;
        #pragma unroll
        for (int k = 0; k < 4; ++k) {
            step(buf[k].x, buf[k].y);      // timestep 2k
            step(buf[k].z, buf[k].w);      // timestep 2k+1
        }
        #pragma unroll
        for (int k = 0; k < 4; ++k) buf[k] = nxt[k];
    }

    // ---- fused dense for rows n0, n0+1 ----
    __shared__ float s_acc[2][HEADS * DIM];   // 2 x 256
    __shared__ float s_part[2][256];
    s_acc[0][h * 64 + j] = h0r;               // Re(hT) row n0
    s_acc[1][h * 64 + j] = h1r;               // Re(hT) row n0+1
    __syncthreads();

    {   // thread t: k-quarter qq = t>>6, col jj = t&63; W loaded once, 2 fma
        int qq = t >> 6, jj = t & 63;
        const float* Wp = W_dense + (qq * 64) * DIM + jj;
        const float* a0 = &s_acc[0][qq * 64];
        const float* a1 = &s_acc[1][qq * 64];
        float part0 = 0.f, part1 = 0.f;
        #pragma unroll 8
        for (int k = 0; k < 64; ++k) {
            float wv = Wp[k * DIM];                 // coalesced, L2-hot
            part0 = fmaf(a0[k], wv, part0);         // LDS broadcast
            part1 = fmaf(a1[k], wv, part1);
        }
        s_part[0][t] = part0;
        s_part[1][t] = part1;
    }
    __syncthreads();
    if (t < 128) {
        int r = t >> 6, c = t & 63;
        y[(n0 + r) * DIM + c] = b_dense[c]
            + s_part[r][c] + s_part[r][64 + c]
            + s_part[r][128 + c] + s_part[r][192 + c];
    }
}

extern "C" void kernel_launch(void* const* d_in, const int* in_sizes, int n_in,
                              void* d_out, int out_size, void* d_ws, size_t ws_size,
                              hipStream_t stream) {
    const float* queries = (const float*)d_in[0];
    const float* values  = (const float*)d_in[1];
    const float* U_re    = (const float*)d_in[2];
    const float* U_im    = (const float*)d_in[3];
    const float* bias    = (const float*)d_in[4];
    const float* theta1  = (const float*)d_in[5];
    const float* phi1    = (const float*)d_in[6];
    const float* theta2  = (const float*)d_in[7];
    const float* phi2    = (const float*)d_in[8];
    const float* omega   = (const float*)d_in[9];
    const float* W_dense = (const float*)d_in[10];
    const float* b_dense = (const float*)d_in[11];
    float* y = (float*)d_out;

    f4* AvP = (f4*)d_ws;   // HEADS*512*64 f4 = 2 MB

    k_av<<<512, 256, 0, stream>>>(values, U_re, U_im, AvP);
    k_rnn_dense<<<512, 256, 0, stream>>>(queries, U_re, U_im, bias, theta1,
                                         phi1, theta2, phi2, omega, AvP,
                                         W_dense, b_dense, y);
}

// Round 3
// 111.162 us; speedup vs baseline: 1.0414x; 1.0137x over previous
//
#include <hip/hip_runtime.h>
#include <math.h>

#define DIM 64
#define HEADS 4
#define BB 8
#define QQ 128
#define VV 128
#define NN (BB*QQ)   // 1024

typedef float f2 __attribute__((ext_vector_type(2)));
typedef float f4 __attribute__((ext_vector_type(4)));

// ---- DPP helpers (VALU, no DS); CTRL is a compile-time template constant ----
template <int CTRL>
__device__ __forceinline__ float dppf(float x) {
    return __int_as_float(__builtin_amdgcn_update_dpp(
        0, __float_as_int(x), CTRL, 0xF, 0xF, true));
}
#define SWAP1 0xB1   // quad_perm(1,0,3,2): xor-1 partner
#define WSHR1 0x138  // wave_shr:1 : lane j <- j-1
#define WSHL1 0x130  // wave_shl:1 : lane j <- j+1

__device__ __forceinline__ f2 b2(float s) { f2 r; r.x = s; r.y = s; return r; }
#define SW(v) __builtin_shufflevector((v), (v), 1, 0)
#define FMA2(a, b, c) __builtin_elementwise_fma((a), (b), (c))

// K1: AvP[h][rp][j] = float4 {re,im of row 2rp ; re,im of row 2rp+1}
//     where (re,im)[row][j] = sum_i values[row,i] * U[h, 64+i, j]
// Packing two V-rows per float4 lets K2 fetch two timesteps per dwordx4.
__global__ __launch_bounds__(256) void k_av(const float* __restrict__ values,
                                            const float* __restrict__ U_re,
                                            const float* __restrict__ U_im,
                                            f4* __restrict__ AvP) {
    int tid = blockIdx.x * blockDim.x + threadIdx.x;
    int w = tid >> 6;            // 0..2047
    int j = tid & 63;
    int h = w >> 9;              // 0..3
    int rp = w & 511;            // row pair within head
    int r0 = rp << 1;
    const float* vrow = values + r0 * DIM;                     // wave-uniform
    const float* ur = U_re + (h * 2 * DIM + DIM) * DIM + j;    // bottom half
    const float* ui = U_im + (h * 2 * DIM + DIM) * DIM + j;
    f2 a0 = 0.f, a1 = 0.f;
    #pragma unroll 8
    for (int i = 0; i < DIM; ++i) {
        f2 u; u.x = ur[i * DIM]; u.y = ui[i * DIM];
        a0 += vrow[i] * u;                 // pk_fma per pair
        a1 += vrow[DIM + i] * u;
    }
    f4 o; o.x = a0.x; o.y = a0.y; o.z = a1.x; o.w = a1.y;
    AvP[(h * 512 + rp) * 64 + j] = o;      // one dwordx4 store
}

// K2: 512 blocks (query-row PAIR) x 4 waves (head per wave); two chains per
// wave share every Av load. Step math is the SAME op sequence as the
// verified kernel, re-expressed on f2 vectors so the backend emits packed
// v_pk_fma_f32 / v_pk_mul_f32 (re,im share every coefficient): ~64 -> ~46
// issued instructions per timestep per wave.
__global__ __launch_bounds__(256, 2) void k_rnn_dense(
        const float* __restrict__ queries,
        const float* __restrict__ U_re,
        const float* __restrict__ U_im,
        const float* __restrict__ bias,
        const float* __restrict__ theta1,
        const float* __restrict__ phi1,
        const float* __restrict__ theta2,
        const float* __restrict__ phi2,
        const float* __restrict__ omega,
        const f4* __restrict__ AvP,
        const float* __restrict__ W_dense,
        const float* __restrict__ b_dense,
        float* __restrict__ y) {
    int m = blockIdx.x;        // 0..511 (row pair)
    int n0 = m << 1;           // rows n0, n0+1 (same batch b)
    int t = threadIdx.x;
    int h = t >> 6;            // head = wave
    int j = t & 63;            // state dim = lane
    int b = n0 >> 7;

    // ---- layer 1 coefficients ----
    int k1 = j >> 1;
    float th1 = theta1[h * 32 + k1], ph1 = phi1[h * 32 + k1];
    float C1 = cosf(th1), s1v = sinf(th1);
    float S1, E1r, E1i;
    if ((j & 1) == 0) { S1 = -s1v; E1r = cosf(ph1); E1i = sinf(ph1); }
    else              { S1 =  s1v; E1r = 1.f;       E1i = 0.f;       }

    // ---- layer 2 coefficients ----
    float C2, SL, SR, p2r, p2i;
    if (j == 0 || j == 63) {
        C2 = 1.f; SL = 0.f; SR = 0.f; p2r = 1.f; p2i = 0.f;
    } else {
        int k2 = (j - 1) >> 1;
        float th2 = theta2[h * 31 + k2], ph2 = phi2[h * 31 + k2];
        float c2 = cosf(th2), s2 = sinf(th2);
        if (j & 1) { C2 = c2; SL = -s2; SR = 0.f; p2r = cosf(ph2); p2i = sinf(ph2); }
        else       { C2 = c2; SR =  s2; SL = 0.f; p2r = 1.f;       p2i = 0.f;       }
    }
    float om = omega[h * 64 + j];
    float eor = cosf(om), eoi = sinf(om);
    float PHr = p2r * eor - p2i * eoi;
    float PHi = p2r * eoi + p2i * eor;
    float bj = bias[h * 64 + j];

    // packed coefficient registers (same value both halves, or (-Im,+Im))
    f2 C1p = b2(C1), S1p = b2(S1), E1rp = b2(E1r);
    f2 E1in; E1in.x = -E1i; E1in.y = E1i;
    f2 C2p = b2(C2), SLp = b2(SL), SRp = b2(SR), PHrp = b2(PHr);
    f2 PHin; PHin.x = -PHi; PHin.y = PHi;

    // ---- Aq for BOTH rows: U column loads shared ----
    const float* q0 = queries + n0 * DIM;        // block-uniform -> s_load
    const float* q1 = q0 + DIM;
    const float* ur = U_re + (h * 2 * DIM) * DIM + j;
    const float* ui = U_im + (h * 2 * DIM) * DIM + j;
    f2 uq0 = 0.f, uq1 = 0.f;
    #pragma unroll 8
    for (int i = 0; i < DIM; ++i) {
        f2 u; u.x = ur[i * DIM]; u.y = ui[i * DIM];
        uq0 = FMA2(b2(q0[i]), u, uq0);
        uq1 = FMA2(b2(q1[i]), u, uq1);
    }

    f2 h0 = 0.f, h1 = 0.f;
    // one timestep for BOTH chains, packed over (re,im). Identical op
    // sequence to the scalar version (fma for fma, mul for mul) -> bitwise
    // same results.
    auto step = [&](f2 av) {
        f2 uv0 = uq0 + av;
        f2 uv1 = uq1 + av;
        // layer 1: p = swap1(h); tp = C1*h + S1*p; T = E1 (.) tp
        f2 p0; p0.x = dppf<SWAP1>(h0.x); p0.y = dppf<SWAP1>(h0.y);
        f2 p1; p1.x = dppf<SWAP1>(h1.x); p1.y = dppf<SWAP1>(h1.y);
        f2 tp0 = FMA2(C1p, h0, S1p * p0);
        f2 tp1 = FMA2(C1p, h1, S1p * p1);
        f2 T0 = FMA2(E1rp, tp0, E1in * SW(tp0));
        f2 T1 = FMA2(E1rp, tp1, E1in * SW(tp1));
        // layer 2: 3-tap + fused phase
        f2 L0; L0.x = dppf<WSHL1>(T0.x); L0.y = dppf<WSHL1>(T0.y);
        f2 L1; L1.x = dppf<WSHL1>(T1.x); L1.y = dppf<WSHL1>(T1.y);
        f2 R0; R0.x = dppf<WSHR1>(T0.x); R0.y = dppf<WSHR1>(T0.y);
        f2 R1; R1.x = dppf<WSHR1>(T1.x); R1.y = dppf<WSHR1>(T1.y);
        f2 sp0 = FMA2(C2p, T0, FMA2(SLp, L0, SRp * R0));
        f2 sp1 = FMA2(C2p, T1, FMA2(SLp, L1, SRp * R1));
        f2 z0 = FMA2(PHrp, sp0, FMA2(PHin, SW(sp0), uv0));
        f2 z1 = FMA2(PHrp, sp1, FMA2(PHin, SW(sp1), uv1));
        // modrelu (scalar tail)
        float q20 = fmaf(z0.x, z0.x, fmaf(z0.y, z0.y, 1e-10f));
        float q21 = fmaf(z1.x, z1.x, fmaf(z1.y, z1.y, 1e-10f));
        float rs0 = __builtin_amdgcn_rsqf(q20);
        float rs1 = __builtin_amdgcn_rsqf(q21);
        float sc0 = fmaxf(fmaf(bj, rs0, 1.f), 0.f);
        float sc1 = fmaxf(fmaf(bj, rs1, 1.f), 0.f);
        h0 = z0 * b2(sc0);
        h1 = z1 * b2(sc1);
    };

    // ---- scan: 64 timestep-pairs, batch-4 (8 steps) register dbuf ----
    const f4* p = AvP + (h * 512 + b * 64) * 64 + j;   // pair stride = 64 f4
    f4 buf[4], nxt[4];
    #pragma unroll
    for (int k = 0; k < 4; ++k) buf[k] = p[k * 64];

    for (int w = 0; w < 16; ++w) {
        const f4* pn = p + ((w < 15) ? 4 * 64 : 0);
        #pragma unroll
        for (int k = 0; k < 4; ++k) nxt[k] = pn[k * 64];
        p = pn;
        #pragma unroll
        for (int k = 0; k < 4; ++k) {
            f2 a; a.x = buf[k].x; a.y = buf[k].y;
            step(a);                       // timestep 2k
            f2 c; c.x = buf[k].z; c.y = buf[k].w;
            step(c);                       // timestep 2k+1
        }
        #pragma unroll
        for (int k = 0; k < 4; ++k) buf[k] = nxt[k];
    }

    // ---- fused dense for rows n0, n0+1 ----
    __shared__ float s_acc[2][HEADS * DIM];   // 2 x 256
    __shared__ float s_part[2][256];
    s_acc[0][h * 64 + j] = h0.x;              // Re(hT) row n0
    s_acc[1][h * 64 + j] = h1.x;              // Re(hT) row n0+1
    __syncthreads();

    {   // thread t: k-quarter qq = t>>6, col jj = t&63; W loaded once, 2 fma
        int qq = t >> 6, jj = t & 63;
        const float* Wp = W_dense + (qq * 64) * DIM + jj;
        const float* a0 = &s_acc[0][qq * 64];
        const float* a1 = &s_acc[1][qq * 64];
        float part0 = 0.f, part1 = 0.f;
        #pragma unroll 8
        for (int k = 0; k < 64; ++k) {
            float wv = Wp[k * DIM];                 // coalesced, L2-hot
            part0 = fmaf(a0[k], wv, part0);         // LDS broadcast
            part1 = fmaf(a1[k], wv, part1);
        }
        s_part[0][t] = part0;
        s_part[1][t] = part1;
    }
    __syncthreads();
    if (t < 128) {
        int r = t >> 6, c = t & 63;
        y[(n0 + r) * DIM + c] = b_dense[c]
            + s_part[r][c] + s_part[r][64 + c]
            + s_part[r][128 + c] + s_part[r][192 + c];
    }
}

extern "C" void kernel_launch(void* const* d_in, const int* in_sizes, int n_in,
                              void* d_out, int out_size, void* d_ws, size_t ws_size,
                              hipStream_t stream) {
    const float* queries = (const float*)d_in[0];
    const float* values  = (const float*)d_in[1];
    const float* U_re    = (const float*)d_in[2];
    const float* U_im    = (const float*)d_in[3];
    const float* bias    = (const float*)d_in[4];
    const float* theta1  = (const float*)d_in[5];
    const float* phi1    = (const float*)d_in[6];
    const float* theta2  = (const float*)d_in[7];
    const float* phi2    = (const float*)d_in[8];
    const float* omega   = (const float*)d_in[9];
    const float* W_dense = (const float*)d_in[10];
    const float* b_dense = (const float*)d_in[11];
    float* y = (float*)d_out;

    f4* AvP = (f4*)d_ws;   // HEADS*512*64 f4 = 2 MB

    k_av<<<512, 256, 0, stream>>>(values, U_re, U_im, AvP);
    k_rnn_dense<<<512, 256, 0, stream>>>(queries, U_re, U_im, bias, theta1,
                                         phi1, theta2, phi2, omega, AvP,
                                         W_dense, b_dense, y);
}